// Round 5
// baseline (776.138 us; speedup 1.0000x reference)
//
#include <hip/hip_runtime.h>
#include <math.h>

// Problem: B=128, P=128, D=128, N=4096, fp32 in/out.
// probs = softmax(10*tanh((A@K)/sqrt(128)) + mask) over n.
constexpr int BB = 128;
constexpr int PP = 128;
constexpr int DD = 128;
constexpr int NN = 4096;
constexpr int NF4 = NN / 4;        // 1024 float4 per row
constexpr float kC = 10.0f;
constexpr float k2InvSqrtD = 0.1767766952966369f;   // 2/sqrt(128)

// Empirical VGPR-cap law (R1-R4): 1024-thr blocks cap at 64 VGPRs (spills);
// 512-thr blocks with (512,2) cap at 128. Design for ~115 live regs.
constexpr int NTHR = 512;          // 8 waves
constexpr int NWAVES = NTHR / 64;
constexpr int PT = 8;              // p-rows per block -> acc = 8x2 float4 = 64 VGPRs

typedef float f32x4 __attribute__((ext_vector_type(4)));

__device__ __forceinline__ float4 ld_nt(const float4* p) {
    f32x4 v = __builtin_nontemporal_load((const f32x4*)p);
    return make_float4(v.x, v.y, v.z, v.w);
}
__device__ __forceinline__ void st_nt(float4* p, float4 s) {
    f32x4 v = {s.x, s.y, s.z, s.w};
    __builtin_nontemporal_store(v, (f32x4*)p);
}

__device__ __forceinline__ float4 f4_fma(float a, float4 k, float4 acc) {
    acc.x = fmaf(a, k.x, acc.x);
    acc.y = fmaf(a, k.y, acc.y);
    acc.z = fmaf(a, k.z, acc.z);
    acc.w = fmaf(a, k.w, acc.w);
    return acc;
}

// clipped = 10*tanh(s/sqrt(128)) + m, via tanh(x) = 1 - 2/(e^{2x}+1)
__device__ __forceinline__ float clip1(float s, float m) {
    const float e2 = __expf(s * k2InvSqrtD);
    const float r = __builtin_amdgcn_rcpf(e2 + 1.0f);
    return fmaf(-2.0f * kC, r, kC) + m;
}

__device__ __forceinline__ float4 f4_clip_mask(float4 s, float4 m) {
    float4 r;
    r.x = clip1(s.x, m.x);
    r.y = clip1(s.y, m.y);
    r.z = clip1(s.z, m.z);
    r.w = clip1(s.w, m.w);
    return r;
}

__device__ __forceinline__ float f4_max(float4 s) {
    return fmaxf(fmaxf(s.x, s.y), fmaxf(s.z, s.w));
}

__device__ __forceinline__ float4 f4_expsub(float4 s, float mx) {
    float4 r;
    r.x = __expf(s.x - mx);
    r.y = __expf(s.y - mx);
    r.z = __expf(s.z - mx);
    r.w = __expf(s.w - mx);
    return r;
}

__device__ __forceinline__ float f4_sum(float4 s) {
    return (s.x + s.y) + (s.z + s.w);
}

__device__ __forceinline__ float4 f4_scale(float4 s, float v) {
    s.x *= v; s.y *= v; s.z *= v; s.w *= v;
    return s;
}

// One d-step for both n-chunks: broadcast-read 8 A values (wave-uniform ->
// LDS broadcast, conflict-free) and FMA into all 8 row accumulators.
__device__ __forceinline__ void fma2(const float (&At)[DD][PT], int d,
                                     float4 ka, float4 kb,
                                     float4 (&acc0)[PT], float4 (&acc1)[PT]) {
    const float4 a0 = *(const float4*)&At[d][0];
    const float4 a1 = *(const float4*)&At[d][4];
    acc0[0] = f4_fma(a0.x, ka, acc0[0]);  acc1[0] = f4_fma(a0.x, kb, acc1[0]);
    acc0[1] = f4_fma(a0.y, ka, acc0[1]);  acc1[1] = f4_fma(a0.y, kb, acc1[1]);
    acc0[2] = f4_fma(a0.z, ka, acc0[2]);  acc1[2] = f4_fma(a0.z, kb, acc1[2]);
    acc0[3] = f4_fma(a0.w, ka, acc0[3]);  acc1[3] = f4_fma(a0.w, kb, acc1[3]);
    acc0[4] = f4_fma(a1.x, ka, acc0[4]);  acc1[4] = f4_fma(a1.x, kb, acc1[4]);
    acc0[5] = f4_fma(a1.y, ka, acc0[5]);  acc1[5] = f4_fma(a1.y, kb, acc1[5]);
    acc0[6] = f4_fma(a1.z, ka, acc0[6]);  acc1[6] = f4_fma(a1.z, kb, acc1[6]);
    acc0[7] = f4_fma(a1.w, ka, acc0[7]);  acc1[7] = f4_fma(a1.w, kb, acc1[7]);
}

__global__ __launch_bounds__(NTHR, 2)   // empirically: 128-VGPR cap
void fused_score_softmax(const float* __restrict__ A,   // [B][P][D]
                         const float* __restrict__ K,   // [B][D][N]
                         const float* __restrict__ M,   // [B][P][N]
                         float* __restrict__ O) {       // [B][P][N]
    __shared__ float At[DD][PT];            // A tile transposed: At[d][p] (4 KB)
    __shared__ float redmax[PT][NWAVES];
    __shared__ float redsum[PT][NWAVES];

    // XCD-aware swizzle: the 16 p-tiles of one batch land on one XCD, so the
    // batch's K rows are shared through that XCD's L2.
    const int l = blockIdx.x;
    const int xcd = l & 7;
    const int j = l >> 3;                   // 0..255 per XCD
    const int b = xcd + 8 * (j >> 4);       // bijective over [0,128)
    const int p_base = (j & 15) * PT;

    const int tid = (int)threadIdx.x;
    const int lane = tid & 63;
    const int wid = tid >> 6;

    // ---- Stage A tile (PT x DD) transposed into LDS (2 elements/thread) ----
    const float* Ab = A + ((size_t)b * PP + p_base) * DD;
    {
        int e = tid;
        At[e & (DD - 1)][e >> 7] = Ab[e];
        e += NTHR;
        At[e & (DD - 1)][e >> 7] = Ab[e];
    }
    __syncthreads();

    // ---- Matmul over d: depth-2 prefetch (2 d-pairs in flight), zero-copy
    // register rotation via 4-phase unroll. Issue-to-use distance = 2 d-steps
    // of FMAs (~256 wave-issue cycles, ~512 wall at 2 waves/SIMD) -> covers
    // L2/L3-class latency.
    const float4* K4 = (const float4*)(K + (size_t)b * DD * NN);
    float4 acc0[PT], acc1[PT];
    #pragma unroll
    for (int p = 0; p < PT; ++p) {
        acc0[p] = make_float4(0.f, 0.f, 0.f, 0.f);
        acc1[p] = make_float4(0.f, 0.f, 0.f, 0.f);
    }

    // X slot: d = t, t+1; Y slot: d = t+2, t+3
    float4 xa0 = K4[0 * NF4 + tid], xb0 = K4[0 * NF4 + NTHR + tid];
    float4 xa1 = K4[1 * NF4 + tid], xb1 = K4[1 * NF4 + NTHR + tid];
    float4 ya0 = K4[2 * NF4 + tid], yb0 = K4[2 * NF4 + NTHR + tid];
    float4 ya1 = K4[3 * NF4 + tid], yb1 = K4[3 * NF4 + NTHR + tid];

    #pragma unroll 1
    for (int t = 0; t < DD; t += 4) {
        fma2(At, t,     xa0, xb0, acc0, acc1);
        fma2(At, t + 1, xa1, xb1, acc0, acc1);
        {   // refill X with d = t+4, t+5 (wraps on last iter; data discarded)
            const int dn = (t + 4) & (DD - 1);
            xa0 = K4[dn * NF4 + tid];       xb0 = K4[dn * NF4 + NTHR + tid];
            xa1 = K4[(dn + 1) * NF4 + tid]; xb1 = K4[(dn + 1) * NF4 + NTHR + tid];
        }
        fma2(At, t + 2, ya0, yb0, acc0, acc1);
        fma2(At, t + 3, ya1, yb1, acc0, acc1);
        {   // refill Y with d = t+6, t+7
            const int dn = (t + 6) & (DD - 1);
            ya0 = K4[dn * NF4 + tid];       yb0 = K4[dn * NF4 + NTHR + tid];
            ya1 = K4[(dn + 1) * NF4 + tid]; yb1 = K4[(dn + 1) * NF4 + NTHR + tid];
        }
    }

    // ---- Pointwise: clip (10*tanh) + mask; per-row thread-local max ----
    const size_t row_off = ((size_t)b * PP + p_base) * NN;
    const float4* M4 = (const float4*)(M + row_off);
    float4* O4 = (float4*)(O + row_off);

    float mx[PT];
    #pragma unroll
    for (int p = 0; p < PT; ++p) {
        const float4 m0 = ld_nt(&M4[p * NF4 + tid]);
        const float4 m1 = ld_nt(&M4[p * NF4 + NTHR + tid]);
        acc0[p] = f4_clip_mask(acc0[p], m0);
        acc1[p] = f4_clip_mask(acc1[p], m1);
        mx[p] = fmaxf(f4_max(acc0[p]), f4_max(acc1[p]));
    }

    // wave max butterfly
    #pragma unroll
    for (int p = 0; p < PT; ++p) {
        float m = mx[p];
        #pragma unroll
        for (int off = 32; off > 0; off >>= 1)
            m = fmaxf(m, __shfl_xor(m, off));
        if (lane == 0) redmax[p][wid] = m;
    }
    __syncthreads();
    #pragma unroll
    for (int p = 0; p < PT; ++p) {
        const float4 r0 = *(const float4*)&redmax[p][0];
        const float4 r1 = *(const float4*)&redmax[p][4];
        mx[p] = fmaxf(f4_max(r0), f4_max(r1));
    }

    // ---- exp(s - max); per-row thread-local sum ----
    float sm[PT];
    #pragma unroll
    for (int p = 0; p < PT; ++p) {
        acc0[p] = f4_expsub(acc0[p], mx[p]);
        acc1[p] = f4_expsub(acc1[p], mx[p]);
        sm[p] = f4_sum(acc0[p]) + f4_sum(acc1[p]);
    }
    #pragma unroll
    for (int p = 0; p < PT; ++p) {
        float s = sm[p];
        #pragma unroll
        for (int off = 32; off > 0; off >>= 1)
            s += __shfl_xor(s, off);
        if (lane == 0) redsum[p][wid] = s;
    }
    __syncthreads();

    // ---- normalize and write (nontemporal: output is write-once) ----
    #pragma unroll
    for (int p = 0; p < PT; ++p) {
        const float4 r0 = *(const float4*)&redsum[p][0];
        const float4 r1 = *(const float4*)&redsum[p][4];
        const float s = f4_sum(r0) + f4_sum(r1);
        const float inv = __builtin_amdgcn_rcpf(s);
        st_nt(&O4[p * NF4 + tid], f4_scale(acc0[p], inv));
        st_nt(&O4[p * NF4 + NTHR + tid], f4_scale(acc1[p], inv));
    }
}

extern "C" void kernel_launch(void* const* d_in, const int* in_sizes, int n_in,
                              void* d_out, int out_size, void* d_ws, size_t ws_size,
                              hipStream_t stream) {
    const float* A = (const float*)d_in[0];   // mh_attn_out [128][128][128]
    const float* K = (const float*)d_in[1];   // single_head_key [128][128][4096]
    const float* M = (const float*)d_in[2];   // mask [128][128][4096]
    float* O = (float*)d_out;                 // probs [128][128][4096]

    const int nblocks = BB * (PP / PT);       // 128 * 16 = 2048
    fused_score_softmax<<<dim3(nblocks), dim3(NTHR), 0, stream>>>(A, K, M, O);
}

// Round 6
// 403.435 us; speedup vs baseline: 1.9238x; 1.9238x over previous
//
#include <hip/hip_runtime.h>
#include <math.h>

// Problem: B=128, P=128, D=128, N=4096, fp32 in/out.
// probs = softmax(10*tanh((A@K)/sqrt(128)) + mask) over n.
constexpr int BB = 128;
constexpr int PP = 128;
constexpr int DD = 128;
constexpr int NN = 4096;
constexpr int NF4 = NN / 4;        // 1024 float4 per row
constexpr float kC = 10.0f;
constexpr float k2InvSqrtD = 0.1767766952966369f;   // 2/sqrt(128)

// Empirical VGPR-cap law (R1-R5): 1024-thr blocks cap at 64 VGPRs (spills);
// 512-thr blocks with (512,2) cap at 128. Design for ~110 live regs.
constexpr int NTHR = 512;          // 8 waves
constexpr int NWAVES = NTHR / 64;
constexpr int PT = 8;              // p-rows per block -> acc = 8x2 float4 = 64 VGPRs
constexpr int DEPTH = 4;           // K ring slots in LDS (16 KB each)

typedef float f32x4 __attribute__((ext_vector_type(4)));

__device__ __forceinline__ float4 ld_nt(const float4* p) {
    f32x4 v = __builtin_nontemporal_load((const f32x4*)p);
    return make_float4(v.x, v.y, v.z, v.w);
}
__device__ __forceinline__ void st_nt(float4* p, float4 s) {
    f32x4 v = {s.x, s.y, s.z, s.w};
    __builtin_nontemporal_store(v, (f32x4*)p);
}

// async global->LDS, 16B per lane: per-lane global addr, wave-uniform LDS base
// (HW scatters to base + lane*16). Tracked by vmcnt.
__device__ __forceinline__ void gload_lds16(const float4* g, float4* l) {
    __builtin_amdgcn_global_load_lds(
        (const __attribute__((address_space(1))) unsigned int*)g,
        (__attribute__((address_space(3))) unsigned int*)l,
        16, 0, 0);
}

__device__ __forceinline__ float4 f4_fma(float a, float4 k, float4 acc) {
    acc.x = fmaf(a, k.x, acc.x);
    acc.y = fmaf(a, k.y, acc.y);
    acc.z = fmaf(a, k.z, acc.z);
    acc.w = fmaf(a, k.w, acc.w);
    return acc;
}

// clipped = 10*tanh(s/sqrt(128)) + m, via tanh(x) = 1 - 2/(e^{2x}+1)
__device__ __forceinline__ float clip1(float s, float m) {
    const float e2 = __expf(s * k2InvSqrtD);
    const float r = __builtin_amdgcn_rcpf(e2 + 1.0f);
    return fmaf(-2.0f * kC, r, kC) + m;
}

__device__ __forceinline__ float4 f4_clip_mask(float4 s, float4 m) {
    float4 r;
    r.x = clip1(s.x, m.x);
    r.y = clip1(s.y, m.y);
    r.z = clip1(s.z, m.z);
    r.w = clip1(s.w, m.w);
    return r;
}

__device__ __forceinline__ float f4_max(float4 s) {
    return fmaxf(fmaxf(s.x, s.y), fmaxf(s.z, s.w));
}

__device__ __forceinline__ float4 f4_expsub(float4 s, float mx) {
    float4 r;
    r.x = __expf(s.x - mx);
    r.y = __expf(s.y - mx);
    r.z = __expf(s.z - mx);
    r.w = __expf(s.w - mx);
    return r;
}

__device__ __forceinline__ float f4_sum(float4 s) {
    return (s.x + s.y) + (s.z + s.w);
}

__device__ __forceinline__ float4 f4_scale(float4 s, float v) {
    s.x *= v; s.y *= v; s.z *= v; s.w *= v;
    return s;
}

// One d-step: 8 wave-uniform A values broadcast from registers, FMA into all
// 8 row accumulators for both n-chunks (64 v_fma per thread-step).
__device__ __forceinline__ void fma2(float4 alo, float4 ahi,
                                     float4 ka, float4 kb,
                                     float4 (&acc0)[PT], float4 (&acc1)[PT]) {
    acc0[0] = f4_fma(alo.x, ka, acc0[0]);  acc1[0] = f4_fma(alo.x, kb, acc1[0]);
    acc0[1] = f4_fma(alo.y, ka, acc0[1]);  acc1[1] = f4_fma(alo.y, kb, acc1[1]);
    acc0[2] = f4_fma(alo.z, ka, acc0[2]);  acc1[2] = f4_fma(alo.z, kb, acc1[2]);
    acc0[3] = f4_fma(alo.w, ka, acc0[3]);  acc1[3] = f4_fma(alo.w, kb, acc1[3]);
    acc0[4] = f4_fma(ahi.x, ka, acc0[4]);  acc1[4] = f4_fma(ahi.x, kb, acc1[4]);
    acc0[5] = f4_fma(ahi.y, ka, acc0[5]);  acc1[5] = f4_fma(ahi.y, kb, acc1[5]);
    acc0[6] = f4_fma(ahi.z, ka, acc0[6]);  acc1[6] = f4_fma(ahi.z, kb, acc1[6]);
    acc0[7] = f4_fma(ahi.w, ka, acc0[7]);  acc1[7] = f4_fma(ahi.w, kb, acc1[7]);
}

__global__ __launch_bounds__(NTHR, 2)   // empirically: 128-VGPR cap
void fused_score_softmax(const float* __restrict__ A,   // [B][P][D]
                         const float* __restrict__ K,   // [B][D][N]
                         const float* __restrict__ M,   // [B][P][N]
                         float* __restrict__ O) {       // [B][P][N]
    __shared__ float At[DD][PT];            // A tile transposed (4 KB)
    __shared__ float4 Ks[DEPTH][NF4];       // K ring: 4 x 16 KB = 64 KB
    __shared__ float redmax[PT][NWAVES];
    __shared__ float redsum[PT][NWAVES];

    // XCD-aware swizzle: the 16 p-tiles of one batch land on one XCD, so the
    // batch's K rows are shared through that XCD's L2.
    const int l = blockIdx.x;
    const int xcd = l & 7;
    const int j = l >> 3;                   // 0..255 per XCD
    const int b = xcd + 8 * (j >> 4);       // bijective over [0,128)
    const int p_base = (j & 15) * PT;

    const int tid = (int)threadIdx.x;
    const int lane = tid & 63;
    const int wid = tid >> 6;

    // ---- Stage A tile (PT x DD) transposed into LDS (2 elements/thread) ----
    const float* Ab = A + ((size_t)b * PP + p_base) * DD;
    {
        int e = tid;
        At[e & (DD - 1)][e >> 7] = Ab[e];
        e += NTHR;
        At[e & (DD - 1)][e >> 7] = Ab[e];
    }
    __syncthreads();   // also drains nothing K-related: ring loads start after

    // ---- K ring staging: wave-private (wave w stages exactly the float4s its
    // own threads read: indices [64w,64w+64) and [512+64w, ...)). No barriers
    // in the main loop; ordering is per-wave via counted vmcnt.
    const float4* K4 = (const float4*)(K + (size_t)b * DD * NN);
    const int wbase = wid * 64;             // wave-uniform

    // prologue: issue slots 0,1,2 (2 loads each; 6 outstanding)
    #pragma unroll
    for (int s = 0; s < DEPTH - 1; ++s) {
        gload_lds16(&K4[s * NF4 + tid],       &Ks[s][wbase]);
        gload_lds16(&K4[s * NF4 + 512 + tid], &Ks[s][512 + wbase]);
    }

    float4 acc0[PT], acc1[PT];
    #pragma unroll
    for (int p = 0; p < PT; ++p) {
        acc0[p] = make_float4(0.f, 0.f, 0.f, 0.f);
        acc1[p] = make_float4(0.f, 0.f, 0.f, 0.f);
    }

    asm volatile("s_waitcnt vmcnt(4)" ::: "memory");   // slot 0 landed
    float4 kXa = Ks[0][tid], kXb = Ks[0][512 + tid];
    float4 aXlo = *(const float4*)&At[0][0];
    float4 aXhi = *(const float4*)&At[0][4];

    #pragma unroll 2
    for (int t = 0; t < DD; t += 2) {
        // phase 1: prefetch Y (d=t+1) from LDS/regs, issue loads for d=t+3,
        // then FMA d=t with X. vmcnt(2): slot t+1 complete, t+2 in flight.
        asm volatile("s_waitcnt vmcnt(2)" ::: "memory");
        const int s1 = (t + 1) & (DEPTH - 1);
        float4 kYa = Ks[s1][tid], kYb = Ks[s1][512 + tid];
        float4 aYlo = *(const float4*)&At[t + 1][0];
        float4 aYhi = *(const float4*)&At[t + 1][4];
        {
            const int dl = (t + 3) & (DD - 1);      // wraps near end (discarded)
            const int sl = (t + 3) & (DEPTH - 1);
            gload_lds16(&K4[dl * NF4 + tid],       &Ks[sl][wbase]);
            gload_lds16(&K4[dl * NF4 + 512 + tid], &Ks[sl][512 + wbase]);
        }
        fma2(aXlo, aXhi, kXa, kXb, acc0, acc1);

        // phase 2: prefetch X (d=t+2), issue loads for d=t+4, FMA d=t+1 with Y.
        asm volatile("s_waitcnt vmcnt(2)" ::: "memory");
        const int s2 = (t + 2) & (DEPTH - 1);
        kXa = Ks[s2][tid]; kXb = Ks[s2][512 + tid];
        const int dn = (t + 2) & (DD - 1);
        aXlo = *(const float4*)&At[dn][0];
        aXhi = *(const float4*)&At[dn][4];
        {
            const int dl = (t + 4) & (DD - 1);
            const int sl = (t + 4) & (DEPTH - 1);
            gload_lds16(&K4[dl * NF4 + tid],       &Ks[sl][wbase]);
            gload_lds16(&K4[dl * NF4 + 512 + tid], &Ks[sl][512 + wbase]);
        }
        fma2(aYlo, aYhi, kYa, kYb, acc0, acc1);
    }

    // ---- Pointwise: clip (10*tanh) + mask; per-row thread-local max ----
    const size_t row_off = ((size_t)b * PP + p_base) * NN;
    const float4* M4 = (const float4*)(M + row_off);
    float4* O4 = (float4*)(O + row_off);

    float mx[PT];
    #pragma unroll
    for (int p = 0; p < PT; ++p) {
        const float4 m0 = ld_nt(&M4[p * NF4 + tid]);
        const float4 m1 = ld_nt(&M4[p * NF4 + NTHR + tid]);
        acc0[p] = f4_clip_mask(acc0[p], m0);
        acc1[p] = f4_clip_mask(acc1[p], m1);
        mx[p] = fmaxf(f4_max(acc0[p]), f4_max(acc1[p]));
    }

    // wave max butterfly
    #pragma unroll
    for (int p = 0; p < PT; ++p) {
        float m = mx[p];
        #pragma unroll
        for (int off = 32; off > 0; off >>= 1)
            m = fmaxf(m, __shfl_xor(m, off));
        if (lane == 0) redmax[p][wid] = m;
    }
    __syncthreads();
    #pragma unroll
    for (int p = 0; p < PT; ++p) {
        const float4 r0 = *(const float4*)&redmax[p][0];
        const float4 r1 = *(const float4*)&redmax[p][4];
        mx[p] = fmaxf(f4_max(r0), f4_max(r1));
    }

    // ---- exp(s - max); per-row thread-local sum ----
    float sm[PT];
    #pragma unroll
    for (int p = 0; p < PT; ++p) {
        acc0[p] = f4_expsub(acc0[p], mx[p]);
        acc1[p] = f4_expsub(acc1[p], mx[p]);
        sm[p] = f4_sum(acc0[p]) + f4_sum(acc1[p]);
    }
    #pragma unroll
    for (int p = 0; p < PT; ++p) {
        float s = sm[p];
        #pragma unroll
        for (int off = 32; off > 0; off >>= 1)
            s += __shfl_xor(s, off);
        if (lane == 0) redsum[p][wid] = s;
    }
    __syncthreads();

    // ---- normalize and write (nontemporal: output is write-once) ----
    #pragma unroll
    for (int p = 0; p < PT; ++p) {
        const float4 r0 = *(const float4*)&redsum[p][0];
        const float4 r1 = *(const float4*)&redsum[p][4];
        const float s = f4_sum(r0) + f4_sum(r1);
        const float inv = __builtin_amdgcn_rcpf(s);
        st_nt(&O4[p * NF4 + tid], f4_scale(acc0[p], inv));
        st_nt(&O4[p * NF4 + NTHR + tid], f4_scale(acc1[p], inv));
    }
}

extern "C" void kernel_launch(void* const* d_in, const int* in_sizes, int n_in,
                              void* d_out, int out_size, void* d_ws, size_t ws_size,
                              hipStream_t stream) {
    const float* A = (const float*)d_in[0];   // mh_attn_out [128][128][128]
    const float* K = (const float*)d_in[1];   // single_head_key [128][128][4096]
    const float* M = (const float*)d_in[2];   // mask [128][128][4096]
    float* O = (float*)d_out;                 // probs [128][128][4096]

    const int nblocks = BB * (PP / PT);       // 128 * 16 = 2048
    fused_score_softmax<<<dim3(nblocks), dim3(NTHR), 0, stream>>>(A, K, M, O);
}